// Round 1
// baseline (292.225 us; speedup 1.0000x reference)
//
#include <hip/hip_runtime.h>

// Problem constants
#define BB 2
#define LL 2048
#define DD 2048
#define NS 16      // d_state
#define RK 64      // dt_rank
#define NP 96      // RK + 2*NS
#define NC 32      // chunks
#define CT 64      // L / NC
#define LOG2E 1.4426950408889634f

#if defined(__has_builtin)
# if __has_builtin(__builtin_amdgcn_exp2f)
#  define EXP2F(v) __builtin_amdgcn_exp2f(v)
# else
#  define EXP2F(v) __expf((v) * 0.6931471805599453f)
# endif
#else
# define EXP2F(v) __expf((v) * 0.6931471805599453f)
#endif

__device__ __forceinline__ float dot4(float4 a, float4 b) {
    return a.x*b.x + a.y*b.y + a.z*b.z + a.w*b.w;
}

// ---------------------------------------------------------------------------
// K1: xp[r][p] = sum_k x[r][k] * Wx[p][k]   r in [0,4096), p in [0,96)
// grid (128, 2) x 256 threads. Tile 32 rows x 48 cols, BK=64.
// ---------------------------------------------------------------------------
__global__ __launch_bounds__(256) void k_proj1(const float* __restrict__ x,
                                               const float* __restrict__ Wx,
                                               float* __restrict__ xp) {
    __shared__ float xs[32][68];   // +4 pad: 272B rows, 16B aligned, conflict-free
    __shared__ float wts[48][68];
    const int tid = threadIdx.x;
    const int r0 = blockIdx.x * 32;
    const int p0 = blockIdx.y * 48;
    const int rq = tid >> 4;   // 0..15 -> rows rq, rq+16
    const int cq = tid & 15;   // 0..15 -> cols cq, cq+16, cq+32
    float acc[2][3] = {{0.f,0.f,0.f},{0.f,0.f,0.f}};

    for (int k0 = 0; k0 < DD; k0 += 64) {
        #pragma unroll
        for (int i = 0; i < 2; ++i) {
            int idx = tid + i*256;          // 0..511 -> 32 rows x 16 float4
            int row = idx >> 4, v = idx & 15;
            *(float4*)&xs[row][v*4] =
                *(const float4*)&x[(size_t)(r0+row)*DD + k0 + v*4];
        }
        #pragma unroll
        for (int i = 0; i < 3; ++i) {
            int idx = tid + i*256;          // 0..767 -> 48 rows x 16 float4
            int row = idx >> 4, v = idx & 15;
            *(float4*)&wts[row][v*4] =
                *(const float4*)&Wx[(size_t)(p0+row)*DD + k0 + v*4];
        }
        __syncthreads();
        #pragma unroll
        for (int k4 = 0; k4 < 16; ++k4) {
            float4 a0 = *(const float4*)&xs[rq][k4*4];
            float4 a1 = *(const float4*)&xs[rq+16][k4*4];
            float4 b0 = *(const float4*)&wts[cq][k4*4];
            float4 b1 = *(const float4*)&wts[cq+16][k4*4];
            float4 b2 = *(const float4*)&wts[cq+32][k4*4];
            acc[0][0] += dot4(a0,b0); acc[0][1] += dot4(a0,b1); acc[0][2] += dot4(a0,b2);
            acc[1][0] += dot4(a1,b0); acc[1][1] += dot4(a1,b1); acc[1][2] += dot4(a1,b2);
        }
        __syncthreads();
    }
    #pragma unroll
    for (int i = 0; i < 2; ++i)
        #pragma unroll
        for (int j = 0; j < 3; ++j)
            xp[(size_t)(r0 + rq + 16*i)*NP + p0 + cq + 16*j] = acc[i][j];
}

// ---------------------------------------------------------------------------
// K2: delta[r][d] = softplus( sum_k xp[r][k] * Wdt[d][k] + bdt[d] ), k<64
// grid (64, 32) x 256 threads. Tile 64 rows x 64 cols, full K in LDS.
// ---------------------------------------------------------------------------
__global__ __launch_bounds__(256) void k_proj2(const float* __restrict__ xp,
                                               const float* __restrict__ Wdt,
                                               const float* __restrict__ bdt,
                                               float* __restrict__ delta) {
    __shared__ float dps[64][68];
    __shared__ float wts[64][68];
    const int tid = threadIdx.x;
    const int r0 = blockIdx.x * 64;
    const int d0 = blockIdx.y * 64;
    const int rq = tid >> 4;   // rows rq + 16*i
    const int cq = tid & 15;   // cols cq + 16*j

    #pragma unroll
    for (int i = 0; i < 4; ++i) {
        int idx = tid + i*256;              // 0..1023 -> 64 rows x 16 float4
        int row = idx >> 4, v = idx & 15;
        *(float4*)&dps[row][v*4] =
            *(const float4*)&xp[(size_t)(r0+row)*NP + v*4];     // delta_p = xp[:, :64]
        *(float4*)&wts[row][v*4] =
            *(const float4*)&Wdt[(size_t)(d0+row)*RK + v*4];
    }
    __syncthreads();

    float acc[4][4];
    #pragma unroll
    for (int i = 0; i < 4; ++i)
        #pragma unroll
        for (int j = 0; j < 4; ++j) acc[i][j] = 0.f;

    #pragma unroll
    for (int k4 = 0; k4 < 16; ++k4) {
        float4 av[4], bv[4];
        #pragma unroll
        for (int i = 0; i < 4; ++i) av[i] = *(const float4*)&dps[rq+16*i][k4*4];
        #pragma unroll
        for (int j = 0; j < 4; ++j) bv[j] = *(const float4*)&wts[cq+16*j][k4*4];
        #pragma unroll
        for (int i = 0; i < 4; ++i)
            #pragma unroll
            for (int j = 0; j < 4; ++j)
                acc[i][j] += dot4(av[i], bv[j]);
    }

    #pragma unroll
    for (int i = 0; i < 4; ++i) {
        int r = r0 + rq + 16*i;
        #pragma unroll
        for (int j = 0; j < 4; ++j) {
            int d = d0 + cq + 16*j;
            float z = acc[i][j] + bdt[d];
            float sp = (z > 20.f) ? z : log1pf(__expf(z));
            delta[(size_t)r*DD + d] = sp;
        }
    }
}

// ---------------------------------------------------------------------------
// K3 (pass 1): per (b, chunk, d): run chunk scan from h=0, store final state
// S[b][c][n][d] and sumdelta[b][c][d].  grid 512 x 256 threads.
// ---------------------------------------------------------------------------
__global__ __launch_bounds__(256) void k_scan1(const float* __restrict__ x,
                                               const float* __restrict__ delta,
                                               const float* __restrict__ xp,
                                               const float* __restrict__ A_log,
                                               float* __restrict__ S,
                                               float* __restrict__ sumdelta) {
    const int bid = blockIdx.x;          // b*256 + c*8 + dq
    const int dq = bid & 7;
    const int c  = (bid >> 3) & (NC-1);
    const int b  = bid >> 8;
    const int d  = dq*256 + threadIdx.x;

    float A2[NS];
    {
        const float4* Ar = (const float4*)&A_log[(size_t)d*NS];
        #pragma unroll
        for (int q = 0; q < 4; ++q) {
            float4 v = Ar[q];
            A2[q*4+0] = -__expf(v.x) * LOG2E;
            A2[q*4+1] = -__expf(v.y) * LOG2E;
            A2[q*4+2] = -__expf(v.z) * LOG2E;
            A2[q*4+3] = -__expf(v.w) * LOG2E;
        }
    }
    float h[NS];
    #pragma unroll
    for (int n = 0; n < NS; ++n) h[n] = 0.f;
    float sd = 0.f;

    const int t0 = c * CT;
    size_t base = ((size_t)b*LL + t0)*DD + d;
    for (int t = t0; t < t0 + CT; ++t) {
        float dlt = delta[base];
        float xv  = x[base];
        sd += dlt;
        float dx = dlt * xv;
        const float4* Bp4 = (const float4*)&xp[((size_t)b*LL + t)*NP + RK];
        float bp[NS];
        *(float4*)&bp[0]  = Bp4[0];
        *(float4*)&bp[4]  = Bp4[1];
        *(float4*)&bp[8]  = Bp4[2];
        *(float4*)&bp[12] = Bp4[3];
        #pragma unroll
        for (int n = 0; n < NS; ++n)
            h[n] = EXP2F(A2[n]*dlt)*h[n] + dx*bp[n];
        base += DD;
    }
    size_t so = ((size_t)(b*NC + c)*NS)*DD + d;
    #pragma unroll
    for (int n = 0; n < NS; ++n) S[so + (size_t)n*DD] = h[n];
    sumdelta[((size_t)(b*NC + c))*DD + d] = sd;
}

// ---------------------------------------------------------------------------
// K4 (pass 2): cross-chunk recurrence, in place: S[c] <- state ENTERING chunk c.
// carry' = exp(A*sumdelta_c)*carry + S_c.  65536 threads: (b, n, d).
// ---------------------------------------------------------------------------
__global__ __launch_bounds__(256) void k_scan2(const float* __restrict__ A_log,
                                               const float* __restrict__ sumdelta,
                                               float* __restrict__ S) {
    const int g = blockIdx.x*256 + threadIdx.x;   // (b*16+n)*2048 + d
    const int d = g & (DD-1);
    const int n = (g >> 11) & (NS-1);
    const int b = g >> 15;
    const float A2 = -__expf(A_log[(size_t)d*NS + n]) * LOG2E;
    float carry = 0.f;
    for (int c = 0; c < NC; ++c) {
        size_t si = ((size_t)(b*NC + c)*NS + n)*DD + d;
        float s  = S[si];
        float sd = sumdelta[((size_t)(b*NC + c))*DD + d];
        S[si] = carry;                       // state entering chunk c
        carry = EXP2F(A2*sd)*carry + s;      // state after chunk c
    }
}

// ---------------------------------------------------------------------------
// K5 (pass 3): replay each chunk from its true incoming state, emit y.
// ---------------------------------------------------------------------------
__global__ __launch_bounds__(256) void k_scan3(const float* __restrict__ x,
                                               const float* __restrict__ delta,
                                               const float* __restrict__ xp,
                                               const float* __restrict__ A_log,
                                               const float* __restrict__ Dv,
                                               const float* __restrict__ S,
                                               float* __restrict__ y) {
    const int bid = blockIdx.x;
    const int dq = bid & 7;
    const int c  = (bid >> 3) & (NC-1);
    const int b  = bid >> 8;
    const int d  = dq*256 + threadIdx.x;

    float A2[NS];
    {
        const float4* Ar = (const float4*)&A_log[(size_t)d*NS];
        #pragma unroll
        for (int q = 0; q < 4; ++q) {
            float4 v = Ar[q];
            A2[q*4+0] = -__expf(v.x) * LOG2E;
            A2[q*4+1] = -__expf(v.y) * LOG2E;
            A2[q*4+2] = -__expf(v.z) * LOG2E;
            A2[q*4+3] = -__expf(v.w) * LOG2E;
        }
    }
    float h[NS];
    size_t so = ((size_t)(b*NC + c)*NS)*DD + d;
    #pragma unroll
    for (int n = 0; n < NS; ++n) h[n] = S[so + (size_t)n*DD];
    const float Dd = Dv[d];

    const int t0 = c * CT;
    size_t base = ((size_t)b*LL + t0)*DD + d;
    for (int t = t0; t < t0 + CT; ++t) {
        float dlt = delta[base];
        float xv  = x[base];
        float dx = dlt * xv;
        const float4* Pr = (const float4*)&xp[((size_t)b*LL + t)*NP + RK];
        float bp[NS], cp[NS];
        *(float4*)&bp[0]  = Pr[0];
        *(float4*)&bp[4]  = Pr[1];
        *(float4*)&bp[8]  = Pr[2];
        *(float4*)&bp[12] = Pr[3];
        *(float4*)&cp[0]  = Pr[4];   // C_proj = xp[:, 80:96]
        *(float4*)&cp[4]  = Pr[5];
        *(float4*)&cp[8]  = Pr[6];
        *(float4*)&cp[12] = Pr[7];
        float yt = 0.f;
        #pragma unroll
        for (int n = 0; n < NS; ++n) {
            h[n] = EXP2F(A2[n]*dlt)*h[n] + dx*bp[n];
            yt += h[n]*cp[n];
        }
        y[base] = yt + xv*Dd;
        base += DD;
    }
}

// ---------------------------------------------------------------------------
extern "C" void kernel_launch(void* const* d_in, const int* in_sizes, int n_in,
                              void* d_out, int out_size, void* d_ws, size_t ws_size,
                              hipStream_t stream) {
    const float* x     = (const float*)d_in[0];
    const float* A_log = (const float*)d_in[1];
    const float* Dv    = (const float*)d_in[2];
    const float* Wx    = (const float*)d_in[3];
    const float* Wdt   = (const float*)d_in[4];
    const float* bdt   = (const float*)d_in[5];
    float* y = (float*)d_out;

    // ws layout (floats): xp[4096*96] | delta[4096*2048] | S[2*32*16*2048] | sumdelta[2*32*2048]
    float* ws    = (float*)d_ws;
    float* xp    = ws;
    float* delta = xp + (size_t)4096*NP;
    float* S     = delta + (size_t)4096*DD;
    float* sumd  = S + (size_t)BB*NC*NS*DD;
    // total = 11,010,048 floats = 44 MB (must be <= ws_size)

    k_proj1<<<dim3(128, 2), 256, 0, stream>>>(x, Wx, xp);
    k_proj2<<<dim3(64, 32), 256, 0, stream>>>(xp, Wdt, bdt, delta);
    k_scan1<<<512, 256, 0, stream>>>(x, delta, xp, A_log, S, sumd);
    k_scan2<<<256, 256, 0, stream>>>(A_log, sumd, S);
    k_scan3<<<512, 256, 0, stream>>>(x, delta, xp, A_log, Dv, S, y);
}

// Round 2
// 151.747 us; speedup vs baseline: 1.9257x; 1.9257x over previous
//
#include <hip/hip_runtime.h>

// Problem constants
#define BB 2
#define LL 2048
#define DD 2048
#define NS 16      // d_state
#define RK 64      // dt_rank
#define NP 96      // RK + 2*NS
#define NC 32      // chunks
#define CT 64      // L / NC
#define KSPLIT 8
#define LOG2E 1.4426950408889634f

#define EXP2F(v) __builtin_amdgcn_exp2f(v)

#define FMA4(acc, a, b)                  \
    acc = fmaf((a).x, (b).x, acc);       \
    acc = fmaf((a).y, (b).y, acc);       \
    acc = fmaf((a).z, (b).z, acc);       \
    acc = fmaf((a).w, (b).w, acc);

// ---------------------------------------------------------------------------
// K1: partial xp for one K-slice.  part[ks][r][p] = sum_{k in slice} x[r][k]*Wx[p][k]
// grid (128 row-blocks, 8 k-slices) x 256 threads. Tile 32 rows x 96 cols, BK=64.
// 4 blocks/CU (LDS 35 KB, VGPR<=128).
// ---------------------------------------------------------------------------
__global__ __launch_bounds__(256, 4) void k_proj1(const float* __restrict__ x,
                                                  const float* __restrict__ Wx,
                                                  float* __restrict__ part) {
    __shared__ float xs[32][68];
    __shared__ float wts[96][68];
    const int tid = threadIdx.x;
    const int r0 = blockIdx.x * 32;
    const int kbase = blockIdx.y * (DD / KSPLIT);   // 256-wide K slice
    const int rq = tid >> 4;   // 0..15 -> rows rq, rq+16
    const int cq = tid & 15;   // 0..15 -> cols cq + 16*j, j=0..5
    float acc[2][6];
    #pragma unroll
    for (int i = 0; i < 2; ++i)
        #pragma unroll
        for (int j = 0; j < 6; ++j) acc[i][j] = 0.f;

    for (int k0 = kbase; k0 < kbase + DD / KSPLIT; k0 += 64) {
        #pragma unroll
        for (int i = 0; i < 2; ++i) {
            int idx = tid + i*256;          // 32 rows x 16 float4
            int row = idx >> 4, v = idx & 15;
            *(float4*)&xs[row][v*4] =
                *(const float4*)&x[(size_t)(r0+row)*DD + k0 + v*4];
        }
        #pragma unroll
        for (int i = 0; i < 6; ++i) {
            int idx = tid + i*256;          // 96 rows x 16 float4
            int row = idx >> 4, v = idx & 15;
            *(float4*)&wts[row][v*4] =
                *(const float4*)&Wx[(size_t)row*DD + k0 + v*4];
        }
        __syncthreads();
        #pragma unroll
        for (int k4 = 0; k4 < 16; ++k4) {
            float4 a0 = *(const float4*)&xs[rq][k4*4];
            float4 a1 = *(const float4*)&xs[rq+16][k4*4];
            #pragma unroll
            for (int j = 0; j < 6; ++j) {
                float4 b = *(const float4*)&wts[cq+16*j][k4*4];
                FMA4(acc[0][j], a0, b);
                FMA4(acc[1][j], a1, b);
            }
        }
        __syncthreads();
    }
    float* pout = part + (size_t)blockIdx.y * 4096 * NP;
    #pragma unroll
    for (int i = 0; i < 2; ++i)
        #pragma unroll
        for (int j = 0; j < 6; ++j)
            pout[(size_t)(r0 + rq + 16*i)*NP + cq + 16*j] = acc[i][j];
}

// ---------------------------------------------------------------------------
// K1b: xp = sum over 8 K-slice partials. 98304 float4s.
// ---------------------------------------------------------------------------
__global__ __launch_bounds__(256) void k_reduce(const float* __restrict__ part,
                                                float* __restrict__ xp) {
    const int i = blockIdx.x*256 + threadIdx.x;   // float4 index, < 98304
    const float4* p = (const float4*)part;
    float4 s = p[i];
    #pragma unroll
    for (int ks = 1; ks < KSPLIT; ++ks) {
        float4 v = p[(size_t)ks*98304 + i];
        s.x += v.x; s.y += v.y; s.z += v.z; s.w += v.w;
    }
    ((float4*)xp)[i] = s;
}

// ---------------------------------------------------------------------------
// K2: delta[r][d] = softplus( sum_k xp[r][k] * Wdt[d][k] + bdt[d] ), k<64
// grid (64, 32) x 256 threads. Tile 64 rows x 64 cols, full K in LDS.
// ---------------------------------------------------------------------------
__global__ __launch_bounds__(256, 4) void k_proj2(const float* __restrict__ xp,
                                                  const float* __restrict__ Wdt,
                                                  const float* __restrict__ bdt,
                                                  float* __restrict__ delta) {
    __shared__ float dps[64][68];
    __shared__ float wts[64][68];
    const int tid = threadIdx.x;
    const int r0 = blockIdx.x * 64;
    const int d0 = blockIdx.y * 64;
    const int rq = tid >> 4;   // rows rq + 16*i
    const int cq = tid & 15;   // cols cq + 16*j

    #pragma unroll
    for (int i = 0; i < 4; ++i) {
        int idx = tid + i*256;              // 64 rows x 16 float4
        int row = idx >> 4, v = idx & 15;
        *(float4*)&dps[row][v*4] =
            *(const float4*)&xp[(size_t)(r0+row)*NP + v*4];     // delta_p = xp[:, :64]
        *(float4*)&wts[row][v*4] =
            *(const float4*)&Wdt[(size_t)(d0+row)*RK + v*4];
    }
    __syncthreads();

    float acc[4][4];
    #pragma unroll
    for (int i = 0; i < 4; ++i)
        #pragma unroll
        for (int j = 0; j < 4; ++j) acc[i][j] = 0.f;

    #pragma unroll 4
    for (int k4 = 0; k4 < 16; ++k4) {
        float4 av[4], bv[4];
        #pragma unroll
        for (int i = 0; i < 4; ++i) av[i] = *(const float4*)&dps[rq+16*i][k4*4];
        #pragma unroll
        for (int j = 0; j < 4; ++j) bv[j] = *(const float4*)&wts[cq+16*j][k4*4];
        #pragma unroll
        for (int i = 0; i < 4; ++i)
            #pragma unroll
            for (int j = 0; j < 4; ++j) {
                FMA4(acc[i][j], av[i], bv[j]);
            }
    }

    #pragma unroll
    for (int i = 0; i < 4; ++i) {
        int r = r0 + rq + 16*i;
        #pragma unroll
        for (int j = 0; j < 4; ++j) {
            int d = d0 + cq + 16*j;
            float z = acc[i][j] + bdt[d];
            // fast softplus: ln(1+e^z); exact enough (threshold 0.29, fp err ~1e-6)
            float sp = (z > 15.f) ? z : __logf(1.f + __expf(z));
            delta[(size_t)r*DD + d] = sp;
        }
    }
}

// ---------------------------------------------------------------------------
// K3 (pass 1): per (b, chunk, d): run chunk scan from h=0, store final state
// S[b][c][n][d] and sumdelta[b][c][d].  grid 512 x 256 threads.
// ---------------------------------------------------------------------------
__global__ __launch_bounds__(256) void k_scan1(const float* __restrict__ x,
                                               const float* __restrict__ delta,
                                               const float* __restrict__ xp,
                                               const float* __restrict__ A_log,
                                               float* __restrict__ S,
                                               float* __restrict__ sumdelta) {
    const int bid = blockIdx.x;          // b*256 + c*8 + dq
    const int dq = bid & 7;
    const int c  = (bid >> 3) & (NC-1);
    const int b  = bid >> 8;
    const int d  = dq*256 + threadIdx.x;

    float A2[NS];
    {
        const float4* Ar = (const float4*)&A_log[(size_t)d*NS];
        #pragma unroll
        for (int q = 0; q < 4; ++q) {
            float4 v = Ar[q];
            A2[q*4+0] = -__expf(v.x) * LOG2E;
            A2[q*4+1] = -__expf(v.y) * LOG2E;
            A2[q*4+2] = -__expf(v.z) * LOG2E;
            A2[q*4+3] = -__expf(v.w) * LOG2E;
        }
    }
    float h[NS];
    #pragma unroll
    for (int n = 0; n < NS; ++n) h[n] = 0.f;
    float sd = 0.f;

    const int t0 = c * CT;
    size_t base = ((size_t)b*LL + t0)*DD + d;
    for (int t = t0; t < t0 + CT; ++t) {
        float dlt = delta[base];
        float xv  = x[base];
        sd += dlt;
        float dx = dlt * xv;
        const float4* Bp4 = (const float4*)&xp[((size_t)b*LL + t)*NP + RK];
        float bp[NS];
        *(float4*)&bp[0]  = Bp4[0];
        *(float4*)&bp[4]  = Bp4[1];
        *(float4*)&bp[8]  = Bp4[2];
        *(float4*)&bp[12] = Bp4[3];
        #pragma unroll
        for (int n = 0; n < NS; ++n)
            h[n] = EXP2F(A2[n]*dlt)*h[n] + dx*bp[n];
        base += DD;
    }
    size_t so = ((size_t)(b*NC + c)*NS)*DD + d;
    #pragma unroll
    for (int n = 0; n < NS; ++n) S[so + (size_t)n*DD] = h[n];
    sumdelta[((size_t)(b*NC + c))*DD + d] = sd;
}

// ---------------------------------------------------------------------------
// K4 (pass 2): cross-chunk recurrence, in place: S[c] <- state ENTERING chunk c.
// carry' = exp(A*sumdelta_c)*carry + S_c.  65536 threads: (b, n, d).
// ---------------------------------------------------------------------------
__global__ __launch_bounds__(256) void k_scan2(const float* __restrict__ A_log,
                                               const float* __restrict__ sumdelta,
                                               float* __restrict__ S) {
    const int g = blockIdx.x*256 + threadIdx.x;   // (b*16+n)*2048 + d
    const int d = g & (DD-1);
    const int n = (g >> 11) & (NS-1);
    const int b = g >> 15;
    const float A2 = -__expf(A_log[(size_t)d*NS + n]) * LOG2E;
    float carry = 0.f;
    for (int c = 0; c < NC; ++c) {
        size_t si = ((size_t)(b*NC + c)*NS + n)*DD + d;
        float s  = S[si];
        float sd = sumdelta[((size_t)(b*NC + c))*DD + d];
        S[si] = carry;                       // state entering chunk c
        carry = EXP2F(A2*sd)*carry + s;      // state after chunk c
    }
}

// ---------------------------------------------------------------------------
// K5 (pass 3): replay each chunk from its true incoming state, emit y.
// ---------------------------------------------------------------------------
__global__ __launch_bounds__(256) void k_scan3(const float* __restrict__ x,
                                               const float* __restrict__ delta,
                                               const float* __restrict__ xp,
                                               const float* __restrict__ A_log,
                                               const float* __restrict__ Dv,
                                               const float* __restrict__ S,
                                               float* __restrict__ y) {
    const int bid = blockIdx.x;
    const int dq = bid & 7;
    const int c  = (bid >> 3) & (NC-1);
    const int b  = bid >> 8;
    const int d  = dq*256 + threadIdx.x;

    float A2[NS];
    {
        const float4* Ar = (const float4*)&A_log[(size_t)d*NS];
        #pragma unroll
        for (int q = 0; q < 4; ++q) {
            float4 v = Ar[q];
            A2[q*4+0] = -__expf(v.x) * LOG2E;
            A2[q*4+1] = -__expf(v.y) * LOG2E;
            A2[q*4+2] = -__expf(v.z) * LOG2E;
            A2[q*4+3] = -__expf(v.w) * LOG2E;
        }
    }
    float h[NS];
    size_t so = ((size_t)(b*NC + c)*NS)*DD + d;
    #pragma unroll
    for (int n = 0; n < NS; ++n) h[n] = S[so + (size_t)n*DD];
    const float Dd = Dv[d];

    const int t0 = c * CT;
    size_t base = ((size_t)b*LL + t0)*DD + d;
    for (int t = t0; t < t0 + CT; ++t) {
        float dlt = delta[base];
        float xv  = x[base];
        float dx = dlt * xv;
        const float4* Pr = (const float4*)&xp[((size_t)b*LL + t)*NP + RK];
        float bp[NS], cp[NS];
        *(float4*)&bp[0]  = Pr[0];
        *(float4*)&bp[4]  = Pr[1];
        *(float4*)&bp[8]  = Pr[2];
        *(float4*)&bp[12] = Pr[3];
        *(float4*)&cp[0]  = Pr[4];   // C_proj = xp[:, 80:96]
        *(float4*)&cp[4]  = Pr[5];
        *(float4*)&cp[8]  = Pr[6];
        *(float4*)&cp[12] = Pr[7];
        float yt = 0.f;
        #pragma unroll
        for (int n = 0; n < NS; ++n) {
            h[n] = EXP2F(A2[n]*dlt)*h[n] + dx*bp[n];
            yt += h[n]*cp[n];
        }
        y[base] = yt + xv*Dd;
        base += DD;
    }
}

// ---------------------------------------------------------------------------
extern "C" void kernel_launch(void* const* d_in, const int* in_sizes, int n_in,
                              void* d_out, int out_size, void* d_ws, size_t ws_size,
                              hipStream_t stream) {
    const float* x     = (const float*)d_in[0];
    const float* A_log = (const float*)d_in[1];
    const float* Dv    = (const float*)d_in[2];
    const float* Wx    = (const float*)d_in[3];
    const float* Wdt   = (const float*)d_in[4];
    const float* bdt   = (const float*)d_in[5];
    float* y = (float*)d_out;

    // ws layout (floats): xp[4096*96] | delta[4096*2048] | S[2*32*16*2048] | sumdelta[2*32*2048]
    // proj1 partials (8*4096*96 = 3.1M floats = 12.6 MB) live temporarily in the
    // delta region (33.5 MB) — delta is written only after k_reduce completes.
    float* ws    = (float*)d_ws;
    float* xp    = ws;
    float* delta = xp + (size_t)4096*NP;
    float* S     = delta + (size_t)4096*DD;
    float* sumd  = S + (size_t)BB*NC*NS*DD;
    float* part  = delta;
    // total = 11,010,048 floats = 44 MB

    k_proj1<<<dim3(128, KSPLIT), 256, 0, stream>>>(x, Wx, part);
    k_reduce<<<384, 256, 0, stream>>>(part, xp);
    k_proj2<<<dim3(64, 32), 256, 0, stream>>>(xp, Wdt, bdt, delta);
    k_scan1<<<512, 256, 0, stream>>>(x, delta, xp, A_log, S, sumd);
    k_scan2<<<256, 256, 0, stream>>>(A_log, sumd, S);
    k_scan3<<<512, 256, 0, stream>>>(x, delta, xp, A_log, Dv, S, y);
}